// Round 2
// baseline (134.165 us; speedup 1.0000x reference)
//
#include <hip/hip_runtime.h>
#include <stdint.h>

#define DIM   1024
#define NEXP  20
#define NFRQ  3000
#define TOPK  5
#define BATCH 64

#define WORDS_PER_ROW (DIM * DIM / 32)   // 32768 uint32 per batch row
#define BITMAP_BYTES  ((size_t)BATCH * WORDS_PER_ROW * 4)  // 8 MiB

// One block per batch row, 64 lanes. Lanes 0..19 each compute one logit
// (dot over 1024 dims), then lane 0 does a serial stable top-5 argmax
// (strict > == first-occurrence tie-break, matching jax.lax.top_k).
// Softmax is monotonic -> top-k on logits == top-k on probs.
__global__ void router_topk_kernel(const float* __restrict__ cls,
                                   const float* __restrict__ W,
                                   const float* __restrict__ bias,
                                   int* __restrict__ expert_out) {
    const int row  = blockIdx.x;   // 0..63
    const int lane = threadIdx.x;  // 0..63

    __shared__ float logits[NEXP];

    if (lane < NEXP) {
        float acc = bias[lane];
        const float* x = cls + (size_t)row * DIM;
        #pragma unroll 8
        for (int d = 0; d < DIM; ++d) {
            acc += x[d] * W[(size_t)d * NEXP + lane];
        }
        logits[lane] = acc;
    }
    __syncthreads();

    if (lane == 0) {
        bool used[NEXP];
        #pragma unroll
        for (int e = 0; e < NEXP; ++e) used[e] = false;
        for (int k = 0; k < TOPK; ++k) {
            int best = 0;
            float bv = -INFINITY;
            for (int e = 0; e < NEXP; ++e) {
                if (!used[e] && logits[e] > bv) { bv = logits[e]; best = e; }
            }
            used[best] = true;
            expert_out[row * TOPK + k] = best;
        }
    }
}

// Set bits in the per-row bitmap. grid = (ceil(NFRQ/256), BATCH*TOPK).
// Bitmap is 8 MiB -> L2-resident; atomics are cheap, collisions rare
// (15000 random bits per 32768-word row).
__global__ void scatter_bits_kernel(const int* __restrict__ expert_idx,
                                    const int* __restrict__ list_indices,
                                    uint32_t* __restrict__ bitmap) {
    const int f  = blockIdx.x * blockDim.x + threadIdx.x;
    const int bk = blockIdx.y;                 // 0 .. BATCH*TOPK-1
    if (f >= NFRQ) return;
    const int b = bk / TOPK;
    const int e = expert_idx[bk];              // broadcast within block
    const int idx = list_indices[(size_t)e * NFRQ + f];   // coalesced over f
    atomicOr(&bitmap[(size_t)b * WORDS_PER_ROW + (idx >> 5)], 1u << (idx & 31));
}

// Expand bitmap -> float output. One float4 (4 bits) per thread:
// perfectly coalesced 16 B/lane stores, bitmap word broadcast to 8 lanes.
// grid covers exactly BATCH*DIM*DIM/4 = 16,777,216 threads.
__global__ void expand_kernel(const uint32_t* __restrict__ bitmap,
                              float4* __restrict__ out) {
    const size_t tid = (size_t)blockIdx.x * blockDim.x + threadIdx.x;
    const uint32_t w = bitmap[tid >> 3];
    const uint32_t s = ((uint32_t)tid & 7u) * 4u;
    float4 v;
    v.x = ((w >> (s + 0)) & 1u) ? 1.0f : 0.0f;
    v.y = ((w >> (s + 1)) & 1u) ? 1.0f : 0.0f;
    v.z = ((w >> (s + 2)) & 1u) ? 1.0f : 0.0f;
    v.w = ((w >> (s + 3)) & 1u) ? 1.0f : 0.0f;
    out[tid] = v;
}

extern "C" void kernel_launch(void* const* d_in, const int* in_sizes, int n_in,
                              void* d_out, int out_size, void* d_ws, size_t ws_size,
                              hipStream_t stream) {
    const float* cls          = (const float*)d_in[0];  // [64,1024]
    const float* W            = (const float*)d_in[1];  // [1024,20]
    const float* bias         = (const float*)d_in[2];  // [20]
    const int*   list_indices = (const int*)d_in[3];    // [20,3000]
    float4*      out          = (float4*)d_out;         // [64,1024,1024]

    uint32_t* bitmap     = (uint32_t*)d_ws;                       // 8 MiB
    int*      expert_idx = (int*)((char*)d_ws + BITMAP_BYTES);    // 64*5 ints

    // 1) router + top-5 (tiny)
    router_topk_kernel<<<dim3(BATCH), dim3(64), 0, stream>>>(cls, W, bias, expert_idx);

    // 2) zero the 8 MiB bitmap (L2-resident, ~2 us)
    hipMemsetAsync(d_ws, 0, BITMAP_BYTES, stream);

    // 3) scatter 960K bits into the bitmap
    dim3 sgrid((NFRQ + 255) / 256, BATCH * TOPK);
    scatter_bits_kernel<<<sgrid, dim3(256), 0, stream>>>(expert_idx, list_indices, bitmap);

    // 4) stream-expand bitmap -> 256 MiB float output (write once, coalesced)
    const size_t n4 = (size_t)out_size / 4;          // 16,777,216 float4s
    const int    block = 256;
    const size_t nblocks = n4 / block;               // 65536
    expand_kernel<<<dim3((uint32_t)nblocks), dim3(block), 0, stream>>>(bitmap, out);
}

// Round 3
// 62.098 us; speedup vs baseline: 2.1605x; 2.1605x over previous
//
#include <hip/hip_runtime.h>
#include <stdint.h>

#define DIM    1024
#define NEXP   20
#define NFRQ   3000
#define TOPK   5
#define BATCH  64

#define CHUNKS        16                       // chunks per row
#define CHUNK_ELEMS   (DIM * DIM / CHUNKS)     // 65536 elements per chunk
#define CHUNK_WORDS   (CHUNK_ELEMS / 32)       // 2048 uint32 LDS bitmap (8 KiB)

// --- Kernel 1: router + top-5 -----------------------------------------------
// One block per batch row, 320 threads (5 waves). Thread t handles
// (expert e = t%20, slice r = t/16? no: r = t/20): partial dot over
// d = r, r+16, ..., r+1008 (64 elems). W-load address = d*20+e = t + 320*i
// -> fully coalesced across the block. LDS reduce, then serial stable top-5
// (strict > == first-index tie-break, matching jax.lax.top_k; softmax is
// monotonic so top-k on logits == top-k on probs).
__global__ void router_topk_kernel(const float* __restrict__ cls,
                                   const float* __restrict__ W,
                                   const float* __restrict__ bias,
                                   int* __restrict__ expert_out) {
    const int row = blockIdx.x;    // 0..63
    const int t   = threadIdx.x;   // 0..319
    const int e   = t % NEXP;
    const int r   = t / NEXP;      // 0..15

    const float* x = cls + (size_t)row * DIM;

    float acc = 0.0f;
    #pragma unroll 16
    for (int i = 0; i < DIM / 16; ++i) {       // 64 iterations
        const int d = r + 16 * i;
        acc += x[d] * W[(size_t)d * NEXP + e]; // coalesced: addr = t + 320*i
    }

    __shared__ float red[320];
    red[t] = acc;
    __syncthreads();

    if (t < NEXP) {
        float s = bias[t];
        #pragma unroll
        for (int rr = 0; rr < 16; ++rr) s += red[t + NEXP * rr];
        red[t] = s;                 // logits now in red[0..19]
    }
    __syncthreads();

    if (t == 0) {
        bool used[NEXP];
        #pragma unroll
        for (int i = 0; i < NEXP; ++i) used[i] = false;
        for (int k = 0; k < TOPK; ++k) {
            int best = 0;
            float bv = -INFINITY;
            for (int i = 0; i < NEXP; ++i) {
                if (!used[i] && red[i] > bv) { bv = red[i]; best = i; }
            }
            used[best] = true;
            expert_out[row * TOPK + k] = best;
        }
    }
}

// --- Kernel 2: fused scatter + expand ---------------------------------------
// grid = (CHUNKS, BATCH), 256 threads. Each block owns one 64K-element chunk
// of one output row. LDS bitmap (8 KiB) is zeroed in-kernel, populated with
// LDS atomics from the row's 5 expert tables (coalesced scans), then the
// chunk is streamed out as coalesced float4 — each output byte written
// exactly once, no global atomics, no global bitmap.
__global__ void scatter_expand_kernel(const int* __restrict__ expert_idx,
                                      const int* __restrict__ list_indices,
                                      float4* __restrict__ out) {
    const int chunk = blockIdx.x;    // 0..15
    const int b     = blockIdx.y;    // 0..63
    const int tid   = threadIdx.x;   // 0..255

    __shared__ uint32_t bm[CHUNK_WORDS];

    #pragma unroll
    for (int i = 0; i < CHUNK_WORDS / 256; ++i) bm[tid + i * 256] = 0u;
    __syncthreads();

    const int lo = chunk * CHUNK_ELEMS;

    for (int k = 0; k < TOPK; ++k) {
        const int e = expert_idx[b * TOPK + k];            // broadcast
        const int* tbl = list_indices + (size_t)e * NFRQ;
        for (int f = tid; f < NFRQ; f += 256) {            // coalesced
            const int idx = tbl[f];
            const uint32_t rel = (uint32_t)(idx - lo);
            if (rel < (uint32_t)CHUNK_ELEMS) {
                atomicOr(&bm[rel >> 5], 1u << (rel & 31)); // LDS atomic
            }
        }
    }
    __syncthreads();

    float4* dst = out + (size_t)b * (DIM * DIM / 4)
                      + (size_t)chunk * (CHUNK_ELEMS / 4);
    #pragma unroll 8
    for (int i = 0; i < CHUNK_ELEMS / 4 / 256; ++i) {      // 64 float4/thread
        const int j = tid + i * 256;
        const uint32_t w = bm[j >> 3];                     // 8 lanes share word
        const uint32_t s = ((uint32_t)j & 7u) * 4u;
        float4 v;
        v.x = ((w >> (s + 0)) & 1u) ? 1.0f : 0.0f;
        v.y = ((w >> (s + 1)) & 1u) ? 1.0f : 0.0f;
        v.z = ((w >> (s + 2)) & 1u) ? 1.0f : 0.0f;
        v.w = ((w >> (s + 3)) & 1u) ? 1.0f : 0.0f;
        dst[j] = v;
    }
}

extern "C" void kernel_launch(void* const* d_in, const int* in_sizes, int n_in,
                              void* d_out, int out_size, void* d_ws, size_t ws_size,
                              hipStream_t stream) {
    const float* cls          = (const float*)d_in[0];  // [64,1024]
    const float* W            = (const float*)d_in[1];  // [1024,20]
    const float* bias         = (const float*)d_in[2];  // [20]
    const int*   list_indices = (const int*)d_in[3];    // [20,3000]
    float4*      out          = (float4*)d_out;         // [64,1024,1024]

    int* expert_idx = (int*)d_ws;                       // 64*5 ints

    router_topk_kernel<<<dim3(BATCH), dim3(320), 0, stream>>>(cls, W, bias, expert_idx);

    scatter_expand_kernel<<<dim3(CHUNKS, BATCH), dim3(256), 0, stream>>>(
        expert_idx, list_indices, out);
}

// Round 4
// 51.794 us; speedup vs baseline: 2.5904x; 1.1990x over previous
//
#include <hip/hip_runtime.h>
#include <stdint.h>

#define DIM    1024
#define NEXP   20
#define NFRQ   3000
#define TOPK   5
#define BATCH  64

#define CHUNKS       32
#define CHUNK_ELEMS  (DIM * DIM / CHUNKS)   // 32768 elements per chunk (2^15)
#define CHUNK_WORDS  (CHUNK_ELEMS / 32)     // 1024 uint32 LDS bitmap (4 KiB)
#define BUCKET_CAP   256                    // expected ~94/bucket, 256 = huge margin

// d_ws layout (in int units)
#define WS_EXPERT_OFF 0      // [BATCH*TOPK]      selected experts
#define WS_COUNTS_OFF 512    // [NEXP*CHUNKS]     bucket counts
#define WS_BINNED_OFF 2048   // [NEXP*CHUNKS*BUCKET_CAP] binned indices (640 KiB)

// --- Kernel 1: router+top5 (blocks 0..63) and index binning (blocks 64..83) --
// Router: 320 threads, thread t = (expert e=t%20, slice r=t/20) sums dims
// d = r+16i -> W address = t + 320*i, fully coalesced. LDS reduce; serial
// stable top-5 (strict > == first-index tie-break, matches jax.lax.top_k;
// softmax monotonic -> top-k on logits == top-k on probs).
// Binning: expert block scans its 3000 indices, buckets by idx>>15 via LDS
// counters, appends to global bucket lists. Bucket ORDER is atomic-order
// nondeterministic but the SET is deterministic; expand only ORs bits.
__global__ void router_and_bin_kernel(const float* __restrict__ cls,
                                      const float* __restrict__ W,
                                      const float* __restrict__ bias,
                                      const int* __restrict__ list_indices,
                                      int* __restrict__ ws) {
    const int t = threadIdx.x;   // 0..319

    __shared__ float red[320];
    __shared__ int lcount[CHUNKS];

    if (blockIdx.x < BATCH) {
        const int row = blockIdx.x;
        const int e   = t % NEXP;
        const int r   = t / NEXP;   // 0..15
        const float* x = cls + (size_t)row * DIM;

        float acc = 0.0f;
        #pragma unroll 16
        for (int i = 0; i < DIM / 16; ++i) {        // 64 iterations
            const int d = r + 16 * i;
            acc += x[d] * W[(size_t)d * NEXP + e];  // coalesced: addr = t + 320*i
        }
        red[t] = acc;
        __syncthreads();

        if (t < NEXP) {
            float s = bias[t];
            #pragma unroll
            for (int rr = 0; rr < 16; ++rr) s += red[t + NEXP * rr];
            red[t] = s;             // logits in red[0..19]
        }
        __syncthreads();

        if (t == 0) {
            bool used[NEXP];
            #pragma unroll
            for (int i = 0; i < NEXP; ++i) used[i] = false;
            for (int k = 0; k < TOPK; ++k) {
                int best = 0;
                float bv = -INFINITY;
                for (int i = 0; i < NEXP; ++i) {
                    if (!used[i] && red[i] > bv) { bv = red[i]; best = i; }
                }
                used[best] = true;
                ws[WS_EXPERT_OFF + row * TOPK + k] = best;
            }
        }
    } else {
        const int e = blockIdx.x - BATCH;           // 0..19
        if (t < CHUNKS) lcount[t] = 0;
        __syncthreads();

        const int* tbl    = list_indices + (size_t)e * NFRQ;
        int*       binned = ws + WS_BINNED_OFF;
        for (int f = t; f < NFRQ; f += 320) {
            const int idx    = tbl[f];              // coalesced
            const int bucket = idx >> 15;           // CHUNK_ELEMS = 2^15
            const int slot   = atomicAdd(&lcount[bucket], 1);
            if (slot < BUCKET_CAP)
                binned[(size_t)(e * CHUNKS + bucket) * BUCKET_CAP + slot] = idx;
        }
        __syncthreads();
        if (t < CHUNKS)
            ws[WS_COUNTS_OFF + e * CHUNKS + t] = min(lcount[t], BUCKET_CAP);
    }
}

// --- Kernel 2: expand -------------------------------------------------------
// grid = (CHUNKS, BATCH) = 2048 blocks, 256 threads (4 waves, 4 KiB LDS ->
// 8 blocks/CU = full 32-wave occupancy). Each block: zero LDS bitmap, pull
// its ~470 pre-binned indices (5 buckets, coalesced), set bits, stream the
// 128 KiB chunk out as coalesced float4 — each output byte written once.
__global__ void expand_kernel(const int* __restrict__ ws,
                              float4* __restrict__ out) {
    const int chunk = blockIdx.x;    // 0..31
    const int b     = blockIdx.y;    // 0..63
    const int tid   = threadIdx.x;   // 0..255

    __shared__ uint32_t bm[CHUNK_WORDS];
    __shared__ int experts[TOPK];

    #pragma unroll
    for (int i = 0; i < CHUNK_WORDS / 256; ++i) bm[tid + i * 256] = 0u;
    if (tid < TOPK) experts[tid] = ws[WS_EXPERT_OFF + b * TOPK + tid];
    __syncthreads();

    const int* binned = ws + WS_BINNED_OFF;
    #pragma unroll
    for (int k = 0; k < TOPK; ++k) {
        const int e = experts[k];                              // uniform
        const int n = ws[WS_COUNTS_OFF + e * CHUNKS + chunk];  // uniform
        const int* seg = binned + (size_t)(e * CHUNKS + chunk) * BUCKET_CAP;
        for (int f = tid; f < n; f += 256) {                   // ~1-2 iters
            const uint32_t rel = (uint32_t)seg[f] & (CHUNK_ELEMS - 1);
            atomicOr(&bm[rel >> 5], 1u << (rel & 31));         // LDS atomic
        }
    }
    __syncthreads();

    float4* dst = out + (size_t)b * (DIM * DIM / 4)
                      + (size_t)chunk * (CHUNK_ELEMS / 4);
    #pragma unroll
    for (int i = 0; i < CHUNK_ELEMS / 4 / 256; ++i) {          // 32 float4/thread
        const int j = tid + i * 256;
        const uint32_t w = bm[j >> 3];                         // 8-lane broadcast
        const uint32_t s = ((uint32_t)j & 7u) * 4u;
        float4 v;
        v.x = ((w >> (s + 0)) & 1u) ? 1.0f : 0.0f;
        v.y = ((w >> (s + 1)) & 1u) ? 1.0f : 0.0f;
        v.z = ((w >> (s + 2)) & 1u) ? 1.0f : 0.0f;
        v.w = ((w >> (s + 3)) & 1u) ? 1.0f : 0.0f;
        dst[j] = v;
    }
}

extern "C" void kernel_launch(void* const* d_in, const int* in_sizes, int n_in,
                              void* d_out, int out_size, void* d_ws, size_t ws_size,
                              hipStream_t stream) {
    const float* cls          = (const float*)d_in[0];  // [64,1024]
    const float* W            = (const float*)d_in[1];  // [1024,20]
    const float* bias         = (const float*)d_in[2];  // [20]
    const int*   list_indices = (const int*)d_in[3];    // [20,3000]
    float4*      out          = (float4*)d_out;         // [64,1024,1024]

    int* ws = (int*)d_ws;   // ~660 KiB used

    // 1) router + top-5 (64 blocks) and expert-table binning (20 blocks)
    router_and_bin_kernel<<<dim3(BATCH + NEXP), dim3(320), 0, stream>>>(
        cls, W, bias, list_indices, ws);

    // 2) expand: bitmap-in-LDS from pre-binned buckets, stream 256 MiB out
    expand_kernel<<<dim3(CHUNKS, BATCH), dim3(256), 0, stream>>>(
        ws, (float4*)out);
}